// Round 6
// baseline (271.641 us; speedup 1.0000x reference)
//
#include <hip/hip_runtime.h>
#include <hip/hip_bf16.h>

// GCN 2-layer, N=100000, E=1.6M, 128->128->64.
// Round 16: dispatch-count attack. k_hist DELETED (histogram fused into
// k_part as a 2-pass chunk scan; bcur is a delta counter memset to 0).
// Weight conversion DELETED (GEMMs read W1/W2 f32 and convert per-fragment
// in-register -> bitwise-identical to pre-converted bf16). k_bucket at 512
// threads (1 node/thread) to halve the serialized passes of the 196-block
// grid-starved kernel. agg/gemm cores unchanged from R15 (proven).

#define IN_F  128
#define HID_F 128
#define OUT_F 64

#define NPB     512    // nodes per bucket (dst>>9)
#define MAXBKT  256    // >= NBKT = ceil(N/512) = 196
#define CHUNK   4096   // edges per workgroup in part
#define SLAB    12288  // slab edges per bucket (mean ~8.2K + pad)
#define CAP     12288  // col staging capacity per bucket (LDS)

typedef __bf16 bf16_t;
typedef __bf16 bf16x4 __attribute__((ext_vector_type(4)));
typedef __bf16 bf16x8 __attribute__((ext_vector_type(8)));
typedef float  f32x2  __attribute__((ext_vector_type(2)));
typedef float  f32x4  __attribute__((ext_vector_type(4)));
typedef unsigned u32x2 __attribute__((ext_vector_type(2)));
typedef unsigned u32x4 __attribute__((ext_vector_type(4)));

// ---------------- pass A+B fused: per-chunk hist + partition ---------------
// packed = (dst&511)<<17 | src  (src < 2^17 since N <= 131072)
// bcur[b*16] is a DELTA counter (memset 0 before launch); final value = raw
// edge count of bucket b. base = b*SLAB + atomicAdd(delta, c).
__global__ __launch_bounds__(256) void k_part(const int* __restrict__ src,
                                              const int* __restrict__ dst, int E,
                                              int* __restrict__ bcur,
                                              unsigned* __restrict__ part, int NBKT) {
    __shared__ int cnt[MAXBKT];
    __shared__ int base[MAXBKT];
    for (int i = threadIdx.x; i < NBKT; i += 256) cnt[i] = 0;
    __syncthreads();
    int cbase = blockIdx.x * CHUNK;
    int cend = min(cbase + CHUNK, E);
    for (int e = cbase + (int)threadIdx.x; e < cend; e += 256)
        atomicAdd(&cnt[dst[e] >> 9], 1);
    __syncthreads();
    int off = (int)((blockIdx.x * 73u) % (unsigned)NBKT);
    for (int j = threadIdx.x; j < NBKT; j += 256) {
        int i = j + off; if (i >= NBKT) i -= NBKT;
        int c = cnt[i];
        base[i] = c ? (i * SLAB + atomicAdd(&bcur[i * 16], c)) : 0;
        cnt[i] = 0;
    }
    __syncthreads();
    for (int e = cbase + (int)threadIdx.x; e < cend; e += 256) {
        int d = dst[e];              // L1-hot re-read
        int b = d >> 9;
        int lp = atomicAdd(&cnt[b], 1);
        part[base[b] + lp] = (unsigned)src[e] | ((unsigned)(d & 511) << 17);
    }
}

// ---------------- pass C: per-bucket CSR finalize (into col slab) ----------
// 512 threads, 1 node/thread. Edge lists padded to multiple of 8 with
// sentinel index N (zero row in h). col written coalesced from LDS stage.
__global__ __launch_bounds__(512) void k_bucket(const unsigned* __restrict__ part,
                                                const int* __restrict__ bcur,
                                                int2* __restrict__ off2,
                                                int* __restrict__ col,
                                                float* __restrict__ dinv, int N) {
    __shared__ int lcnt[NPB];     // 2 KB
    __shared__ int lexc[NPB];     // 2 KB
    __shared__ int lcur[NPB];     // 2 KB
    __shared__ int psum[NPB];     // 2 KB
    __shared__ int stage[CAP];    // 48 KB
    int b = blockIdx.x;
    int t = threadIdx.x;
    int node0 = b * NPB;
    int e0s = b * SLAB;
    int cnt = bcur[b * 16];       // delta counter == raw count
    lcnt[t] = 0;
    __syncthreads();
    for (int i = t; i < cnt; i += 512)
        atomicAdd(&lcnt[part[e0s + i] >> 17], 1);
    __syncthreads();
    int pc = (lcnt[t] + 7) & ~7;
    psum[t] = pc;
    __syncthreads();
    for (int ofs = 1; ofs < NPB; ofs <<= 1) {
        int add = (t >= ofs) ? psum[t - ofs] : 0;
        __syncthreads();
        psum[t] += add;
        __syncthreads();
    }
    int run = psum[t] - pc;       // exclusive padded start
    lexc[t] = run;
    lcur[t] = run;
    int node = node0 + t;
    if (node < N) {
        off2[node] = make_int2(e0s + run, e0s + run + pc);
        dinv[node] = rsqrtf((float)lcnt[t] + 1.0f);
    }
    __syncthreads();
    for (int i = t; i < cnt; i += 512) {
        unsigned p = part[e0s + i];
        int dl = p >> 17;
        int sv = (int)(p & 0x1FFFF);
        int lp = atomicAdd(&lcur[dl], 1);
        if (lp < CAP) stage[lp] = sv;
        else col[e0s + lp] = sv;  // statistically unreachable
    }
    __syncthreads();
    {
        int en = lexc[t] + pc;
        for (int i = lcur[t]; i < en; i++) {   // <= 7 pad slots per node
            if (i < CAP) stage[i] = N; else col[e0s + i] = N;
        }
    }
    __syncthreads();
    int tot = psum[NPB - 1];
    for (int i = t; i < tot && i < CAP; i += 512) col[e0s + i] = stage[i];
}

// ---------------- MFMA GEMM + row-scale epilogue (layer 1) ----------------
// H[n,m] = scale[n] * sum_k X[n,k]*W[m,k], K=128, H stored bf16 row-major.
// W read as f32, converted per-fragment (identical cast to offline conv).
// Row N of H is written as zeros (gather sentinel for padded edge slots).
template <int NCOL, typename TIN>
__global__ __launch_bounds__(256) void k_gemm_mfma(const TIN* __restrict__ X,
                                                   const float* __restrict__ W,
                                                   const float* __restrict__ scale,
                                                   bf16_t* __restrict__ H, int N) {
    constexpr int CT = NCOL / 16;
    int wv = threadIdx.x >> 6, lane = threadIdx.x & 63;
    int quad = lane >> 4, l16 = lane & 15;
    int row0 = blockIdx.x * 128 + wv * 32;
    f32x4 acc[2][CT] = {};
#pragma unroll
    for (int ks = 0; ks < 4; ks++) {
        int k0 = ks * 32 + quad * 8;
        bf16x8 a[2];
#pragma unroll
        for (int rt = 0; rt < 2; rt++) {
            int r = row0 + rt * 16 + l16;
            if (r >= N) r = N - 1;
            const TIN* p = X + (size_t)r * 128 + k0;
            if constexpr (sizeof(TIN) == 4) {
                f32x4 x0 = *(const f32x4*)p;
                f32x4 x1 = *(const f32x4*)(p + 4);
                bf16x8 tt;
                tt[0] = (bf16_t)x0[0]; tt[1] = (bf16_t)x0[1];
                tt[2] = (bf16_t)x0[2]; tt[3] = (bf16_t)x0[3];
                tt[4] = (bf16_t)x1[0]; tt[5] = (bf16_t)x1[1];
                tt[6] = (bf16_t)x1[2]; tt[7] = (bf16_t)x1[3];
                a[rt] = tt;
            } else {
                a[rt] = *(const bf16x8*)p;
            }
        }
#pragma unroll
        for (int ct = 0; ct < CT; ct++) {
            const float* wp = W + (size_t)(ct * 16 + l16) * 128 + k0;
            f32x4 w0 = *(const f32x4*)wp;
            f32x4 w1 = *(const f32x4*)(wp + 4);
            bf16x8 bfrag;
            bfrag[0] = (bf16_t)w0[0]; bfrag[1] = (bf16_t)w0[1];
            bfrag[2] = (bf16_t)w0[2]; bfrag[3] = (bf16_t)w0[3];
            bfrag[4] = (bf16_t)w1[0]; bfrag[5] = (bf16_t)w1[1];
            bfrag[6] = (bf16_t)w1[2]; bfrag[7] = (bf16_t)w1[3];
#pragma unroll
            for (int rt = 0; rt < 2; rt++)
                acc[rt][ct] = __builtin_amdgcn_mfma_f32_16x16x32_bf16(a[rt], bfrag, acc[rt][ct], 0, 0, 0);
        }
    }
#pragma unroll
    for (int rt = 0; rt < 2; rt++)
#pragma unroll
        for (int r4 = 0; r4 < 4; r4++) {
            int r = row0 + rt * 16 + quad * 4 + r4;
            if (r < N) {
                float sc = scale[r];
#pragma unroll
                for (int ct = 0; ct < CT; ct++)
                    H[(size_t)r * NCOL + ct * 16 + l16] = (bf16_t)(sc * acc[rt][ct][r4]);
            } else if (r == N) {
#pragma unroll
                for (int ct = 0; ct < CT; ct++)
                    H[(size_t)N * NCOL + ct * 16 + l16] = (bf16_t)0.f;
            }
        }
}

// ---------------- gather helpers ----------------
template <int ROWE>
__device__ __forceinline__ void gather8(const bf16_t* __restrict__ hp,
                                        const int* __restrict__ col, int e,
                                        u32x4* w) {
    int4 c0 = *(const int4*)(col + e);
    int4 c1 = *(const int4*)(col + e + 4);
    w[0] = *(const u32x4*)(hp + (unsigned)c0.x * (unsigned)ROWE);
    w[1] = *(const u32x4*)(hp + (unsigned)c0.y * (unsigned)ROWE);
    w[2] = *(const u32x4*)(hp + (unsigned)c0.z * (unsigned)ROWE);
    w[3] = *(const u32x4*)(hp + (unsigned)c0.w * (unsigned)ROWE);
    w[4] = *(const u32x4*)(hp + (unsigned)c1.x * (unsigned)ROWE);
    w[5] = *(const u32x4*)(hp + (unsigned)c1.y * (unsigned)ROWE);
    w[6] = *(const u32x4*)(hp + (unsigned)c1.z * (unsigned)ROWE);
    w[7] = *(const u32x4*)(hp + (unsigned)c1.w * (unsigned)ROWE);
}

__device__ __forceinline__ void accum8(const u32x4* w, f32x2* a2) {
#pragma unroll
    for (int u = 0; u < 8; u++)
#pragma unroll
        for (int k = 0; k < 4; k++) {
            f32x2 v;
            v.x = __uint_as_float(w[u][k] << 16);
            v.y = __uint_as_float(w[u][k] & 0xffff0000u);
            a2[k] += v;                       // v_pk_add_f32
        }
}

// ---------------- fused agg128 + gemm64 (layer-1 agg + layer-2 GEMM) -------
// 16 lanes/node, 4 nodes/wave, 16 nodes/block. Aggregate h1 + relu in regs,
// stage the 16x128 tile in LDS, then 4-wave MFMA 128->64 with dinv scale,
// writing h2 bf16 (+ zero row N). W2 read f32, converted per-fragment.
__global__ __launch_bounds__(256) void k_agg_gemm(const bf16_t* __restrict__ h,
                                                  const int2* __restrict__ off2,
                                                  const int* __restrict__ col,
                                                  const float* __restrict__ dinv,
                                                  const float* __restrict__ bias,
                                                  const float* __restrict__ W2,
                                                  bf16_t* __restrict__ h2, int N) {
    __shared__ float hl[16][132];   // +4 pad: 2-way-max bank aliasing
    __shared__ float dl[16];
    int lane = threadIdx.x & 63;
    int wv = threadIdx.x >> 6;
    int g = lane >> 4, fl = lane & 15;
    int node0 = blockIdx.x * 16;
    int node = node0 + wv * 4 + g;
    bool alive = node < N;
    int f = fl * 8;
    const bf16_t* hp = h + f;
    f32x2 a2[4] = {};
    float di = 0.f;
    if (alive) {
        u32x4 ws = *(const u32x4*)(hp + (unsigned)node * 128u);   // self row
        int2 oe = off2[node];
        di = dinv[node];
#pragma unroll
        for (int k = 0; k < 4; k++) {
            f32x2 v;
            v.x = __uint_as_float(ws[k] << 16);
            v.y = __uint_as_float(ws[k] & 0xffff0000u);
            a2[k] = v;
        }
        u32x4 w[8];
        for (int e = oe.x; e < oe.y; e += 8) {
            gather8<128>(hp, col, e, w);
            accum8(w, a2);
        }
    }
    f32x4 b0 = *(const f32x4*)(bias + f);
    f32x4 b1 = *(const f32x4*)(bias + f + 4);
    int lr = wv * 4 + g;
#pragma unroll
    for (int j = 0; j < 8; j++) {
        float bv = (j < 4) ? b0[j] : b1[j - 4];
        float val = a2[j >> 1][j & 1] * di + bv;
        hl[lr][f + j] = fmaxf(val, 0.f);        // relu'd h1r row in LDS
    }
    if (fl == 0) dl[lr] = di;
    __syncthreads();

    // mini-GEMM: wave wv computes output cols [wv*16, wv*16+16)
    int quad = lane >> 4, l16 = lane & 15;
    f32x4 c4 = {0.f, 0.f, 0.f, 0.f};
#pragma unroll
    for (int ks = 0; ks < 4; ks++) {
        int k0 = ks * 32 + quad * 8;
        bf16x8 afr;
#pragma unroll
        for (int j = 0; j < 8; j++) afr[j] = (bf16_t)hl[l16][k0 + j];
        const float* wp = W2 + (size_t)(wv * 16 + l16) * 128 + k0;
        f32x4 w0 = *(const f32x4*)wp;
        f32x4 w1 = *(const f32x4*)(wp + 4);
        bf16x8 bfr;
        bfr[0] = (bf16_t)w0[0]; bfr[1] = (bf16_t)w0[1];
        bfr[2] = (bf16_t)w0[2]; bfr[3] = (bf16_t)w0[3];
        bfr[4] = (bf16_t)w1[0]; bfr[5] = (bf16_t)w1[1];
        bfr[6] = (bf16_t)w1[2]; bfr[7] = (bf16_t)w1[3];
        c4 = __builtin_amdgcn_mfma_f32_16x16x32_bf16(afr, bfr, c4, 0, 0, 0);
    }
#pragma unroll
    for (int r4 = 0; r4 < 4; r4++) {
        int rr = quad * 4 + r4;
        int gn = node0 + rr;
        if (gn < N)
            h2[(size_t)gn * 64 + wv * 16 + l16] = (bf16_t)(dl[rr] * c4[r4]);
    }
    if (blockIdx.x == 0 && threadIdx.x < 32)    // zero sentinel row N of h2
        ((unsigned*)h2)[(size_t)N * 32 + threadIdx.x] = 0u;
}

// ---------------- agg, generic: LPN lanes/node, 64/LPN nodes/wave ---------
template <int ROWE, int LPN, bool RELU, typename TOUT>
__global__ __launch_bounds__(256) void k_agg(const bf16_t* __restrict__ h,
                                             const int2* __restrict__ off2,
                                             const int* __restrict__ col,
                                             const float* __restrict__ dinv,
                                             const float* __restrict__ bias,
                                             TOUT* __restrict__ out, int N) {
    constexpr int NPW = 64 / LPN;   // nodes per wave
    int lane = threadIdx.x & 63;
    int wv = threadIdx.x >> 6;
    int g = lane / LPN, fl = lane % LPN;
    int node = blockIdx.x * (4 * NPW) + wv * NPW + g;
    if (node >= N) return;
    int f = fl * 8;
    const bf16_t* hp = h + f;
    u32x4 ws = *(const u32x4*)(hp + (unsigned)node * (unsigned)ROWE); // self row
    int2 oe = off2[node];
    float di = dinv[node];
    f32x2 a2[4];
#pragma unroll
    for (int k = 0; k < 4; k++) {
        f32x2 v;
        v.x = __uint_as_float(ws[k] << 16);
        v.y = __uint_as_float(ws[k] & 0xffff0000u);
        a2[k] = v;
    }
    u32x4 w[8];
    for (int e = oe.x; e < oe.y; e += 8) {
        gather8<ROWE>(hp, col, e, w);
        accum8(w, a2);
    }
    f32x4 b0 = *(const f32x4*)(bias + f);
    f32x4 b1 = *(const f32x4*)(bias + f + 4);
    float r[8];
#pragma unroll
    for (int j = 0; j < 8; j++) {
        float bv = (j < 4) ? b0[j] : b1[j - 4];
        float val = a2[j >> 1][j & 1] * di + bv;
        if (RELU) val = fmaxf(val, 0.f);
        r[j] = val;
    }
    if constexpr (sizeof(TOUT) == 2) {
        bf16x8 v;
#pragma unroll
        for (int j = 0; j < 8; j++) v[j] = (bf16_t)r[j];
        *(bf16x8*)((bf16_t*)out + (size_t)node * ROWE + f) = v;
    } else {
        f32x4 v0 = {r[0], r[1], r[2], r[3]};
        f32x4 v1 = {r[4], r[5], r[6], r[7]};
        *(f32x4*)((float*)out + (size_t)node * ROWE + f) = v0;
        *(f32x4*)((float*)out + (size_t)node * ROWE + f + 4) = v1;
    }
}

extern "C" void kernel_launch(void* const* d_in, const int* in_sizes, int n_in,
                              void* d_out, int out_size, void* d_ws, size_t ws_size,
                              hipStream_t stream) {
    const float* x  = (const float*)d_in[0];
    const float* W1 = (const float*)d_in[1];
    const float* b1 = (const float*)d_in[2];
    const float* W2 = (const float*)d_in[3];
    const float* b2 = (const float*)d_in[4];
    const int*   ei = (const int*)d_in[5];

    int N = in_sizes[0] / IN_F;
    int E = in_sizes[5] / 2;
    const int* src = ei;
    const int* dst = ei + E;
    int NBKT = (N + NPB - 1) / NPB;           // 196
    int pchunks = (E + CHUNK - 1) / CHUNK;    // 391

    size_t woff = 0;
    auto alloc = [&](size_t bytes) {
        void* p = (char*)d_ws + woff;
        woff += (bytes + 255) & ~(size_t)255;
        return p;
    };
    int*      bcur  = (int*)alloc((size_t)NBKT * 16 * 4);   // 64B line per bucket
    unsigned* part  = (unsigned*)alloc((size_t)NBKT * SLAB * 4);
    int*      col   = (int*)alloc((size_t)NBKT * SLAB * 4);
    int2*     off2  = (int2*)alloc((size_t)N * 8);
    float*    dinv  = (float*)alloc((size_t)N * 4);
    bf16_t*   h1    = (bf16_t*)alloc((size_t)(N + 1) * HID_F * 2);  // +1 zero row
    bf16_t*   h2b   = (bf16_t*)alloc((size_t)(N + 1) * OUT_F * 2);  // +1 zero row
    float*    outp  = (float*)d_out;

    hipMemsetAsync(bcur, 0, (size_t)NBKT * 16 * 4, stream);
    k_part<<<pchunks, 256, 0, stream>>>(src, dst, E, bcur, part, NBKT);
    k_bucket<<<NBKT, 512, 0, stream>>>(part, bcur, off2, col, dinv, N);

    int gemm_blocks = (N + 127) / 128;

    // layer 1: h1 = dinv * (x@W1^T)  [bf16, +zero row N]
    k_gemm_mfma<HID_F, float><<<gemm_blocks, 256, 0, stream>>>(x, W1, dinv, h1, N);
    // fused: agg(h1)+relu -> (in LDS) @ W2^T -> dinv-scale -> h2 [bf16]
    k_agg_gemm<<<(N + 15) / 16, 256, 0, stream>>>(h1, off2, col, dinv, b1, W2, h2b, N);
    // layer 2 agg: gather h2 -> fp32 out
    k_agg<OUT_F, 8, false, float><<<(N + 31) / 32, 256, 0, stream>>>(h2b, off2, col, dinv, b2, outp, N);
}

// Round 7
// 251.934 us; speedup vs baseline: 1.0782x; 1.0782x over previous
//
#include <hip/hip_runtime.h>
#include <hip/hip_bf16.h>

// GCN 2-layer, N=100000, E=1.6M, 128->128->64.
// Round 17:
//  - Weights back to PRE-CONVERTED bf16 (R6's in-register f32 conversion cost
//    7us in agg_gemm's serial mini-GEMM). k_pre (97 blocks) converts W1/W2
//    and zeros bcur (replaces memset dispatch).
//  - k_part scatter COALESCED: chunk-local counting sort in LDS (scan of 196
//    bucket counts -> scatter payload+bktid into LDS -> linear writeout).
//    Store instructions now span ~3 bucket runs instead of ~64 -> ~20x fewer
//    L2 write transactions.
//  - k_bucket / gemm / agg cores unchanged (proven).

#define IN_F  128
#define HID_F 128
#define OUT_F 64

#define NPB     512    // nodes per bucket (dst>>9)
#define MAXBKT  256    // >= NBKT = ceil(N/512) = 196
#define CHUNK   4096   // edges per workgroup in part
#define SLAB    12288  // slab edges per bucket (mean ~8.2K + pad)
#define CAP     12288  // col staging capacity per bucket (LDS)

typedef __bf16 bf16_t;
typedef __bf16 bf16x4 __attribute__((ext_vector_type(4)));
typedef __bf16 bf16x8 __attribute__((ext_vector_type(8)));
typedef float  f32x2  __attribute__((ext_vector_type(2)));
typedef float  f32x4  __attribute__((ext_vector_type(4)));
typedef unsigned u32x2 __attribute__((ext_vector_type(2)));
typedef unsigned u32x4 __attribute__((ext_vector_type(4)));

// ---------------- pass 0: weight conversion + bcur zero --------------------
__global__ __launch_bounds__(256) void k_pre(const float* __restrict__ W1s,
                                             const float* __restrict__ W2s,
                                             bf16_t* __restrict__ Wdst,
                                             int n1, int n2,
                                             int* __restrict__ bcur, int nb16) {
    int i = blockIdx.x * 256 + threadIdx.x;
    if (i < n1) Wdst[i] = (bf16_t)W1s[i];
    else if (i < n1 + n2) Wdst[i] = (bf16_t)W2s[i - n1];
    if (blockIdx.x == gridDim.x - 1) {
        for (int j = threadIdx.x; j < nb16; j += 256) bcur[j] = 0;
    }
}

// ---------------- pass B: partition via chunk-local counting sort ----------
// packed = (dst&511)<<17 | src  (src < 2^17 since N <= 131072)
// bcur[b*16] delta counter (zeroed by k_pre); final value = raw bucket count.
__global__ __launch_bounds__(256) void k_part(const int* __restrict__ src,
                                              const int* __restrict__ dst, int E,
                                              int* __restrict__ bcur,
                                              unsigned* __restrict__ part, int NBKT) {
    __shared__ int cnt[MAXBKT];
    __shared__ int base[MAXBKT];
    __shared__ int cstart[MAXBKT];         // chunk-local exclusive start
    __shared__ unsigned stg[CHUNK];        // 16 KB payload
    __shared__ unsigned short sbk[CHUNK];  // 8 KB bucket id
    int t = threadIdx.x;
    cnt[t] = 0;
    __syncthreads();
    int cbase = blockIdx.x * CHUNK;
    int cend = min(cbase + CHUNK, E);
    int clen = cend - cbase;
    for (int e = cbase + t; e < cend; e += 256)
        atomicAdd(&cnt[dst[e] >> 9], 1);
    __syncthreads();
    int c = cnt[t];
    cstart[t] = c;
    __syncthreads();
    for (int ofs = 1; ofs < 256; ofs <<= 1) {     // inclusive scan
        int add = (t >= ofs) ? cstart[t - ofs] : 0;
        __syncthreads();
        cstart[t] += add;
        __syncthreads();
    }
    int excl = cstart[t] - c;
    __syncthreads();
    cstart[t] = excl;                              // exclusive
    base[t] = (c && t < NBKT) ? (t * SLAB + atomicAdd(&bcur[t * 16], c)) : 0;
    cnt[t] = 0;
    __syncthreads();
    for (int e = cbase + t; e < cend; e += 256) {
        int d = dst[e];                            // L2-hot re-read
        int b = d >> 9;
        int lp = atomicAdd(&cnt[b], 1);
        int pos = cstart[b] + lp;
        stg[pos] = (unsigned)src[e] | ((unsigned)(d & 511) << 17);
        sbk[pos] = (unsigned short)b;
    }
    __syncthreads();
    for (int i = t; i < clen; i += 256) {          // coalesced run writeout
        int b = sbk[i];
        part[base[b] + (i - cstart[b])] = stg[i];
    }
}

// ---------------- pass C: per-bucket CSR finalize (into col slab) ----------
// 512 threads, 1 node/thread. Edge lists padded to multiple of 8 with
// sentinel index N (zero row in h). col written coalesced from LDS stage.
__global__ __launch_bounds__(512) void k_bucket(const unsigned* __restrict__ part,
                                                const int* __restrict__ bcur,
                                                int2* __restrict__ off2,
                                                int* __restrict__ col,
                                                float* __restrict__ dinv, int N) {
    __shared__ int lcnt[NPB];     // 2 KB
    __shared__ int lexc[NPB];     // 2 KB
    __shared__ int lcur[NPB];     // 2 KB
    __shared__ int psum[NPB];     // 2 KB
    __shared__ int stage[CAP];    // 48 KB
    int b = blockIdx.x;
    int t = threadIdx.x;
    int node0 = b * NPB;
    int e0s = b * SLAB;
    int cnt = bcur[b * 16];       // delta counter == raw count
    lcnt[t] = 0;
    __syncthreads();
    for (int i = t; i < cnt; i += 512)
        atomicAdd(&lcnt[part[e0s + i] >> 17], 1);
    __syncthreads();
    int pc = (lcnt[t] + 7) & ~7;
    psum[t] = pc;
    __syncthreads();
    for (int ofs = 1; ofs < NPB; ofs <<= 1) {
        int add = (t >= ofs) ? psum[t - ofs] : 0;
        __syncthreads();
        psum[t] += add;
        __syncthreads();
    }
    int run = psum[t] - pc;       // exclusive padded start
    lexc[t] = run;
    lcur[t] = run;
    int node = node0 + t;
    if (node < N) {
        off2[node] = make_int2(e0s + run, e0s + run + pc);
        dinv[node] = rsqrtf((float)lcnt[t] + 1.0f);
    }
    __syncthreads();
    for (int i = t; i < cnt; i += 512) {
        unsigned p = part[e0s + i];
        int dl = p >> 17;
        int sv = (int)(p & 0x1FFFF);
        int lp = atomicAdd(&lcur[dl], 1);
        if (lp < CAP) stage[lp] = sv;
        else col[e0s + lp] = sv;  // statistically unreachable
    }
    __syncthreads();
    {
        int en = lexc[t] + pc;
        for (int i = lcur[t]; i < en; i++) {   // <= 7 pad slots per node
            if (i < CAP) stage[i] = N; else col[e0s + i] = N;
        }
    }
    __syncthreads();
    int tot = psum[NPB - 1];
    for (int i = t; i < tot && i < CAP; i += 512) col[e0s + i] = stage[i];
}

// ---------------- MFMA GEMM + row-scale epilogue (layer 1) ----------------
// H[n,m] = scale[n] * sum_k X[n,k]*W[m,k], K=128, H stored bf16 row-major.
// Row N of H is written as zeros (gather sentinel for padded edge slots).
template <int NCOL, typename TIN>
__global__ __launch_bounds__(256) void k_gemm_mfma(const TIN* __restrict__ X,
                                                   const bf16_t* __restrict__ W,
                                                   const float* __restrict__ scale,
                                                   bf16_t* __restrict__ H, int N) {
    constexpr int CT = NCOL / 16;
    int wv = threadIdx.x >> 6, lane = threadIdx.x & 63;
    int quad = lane >> 4, l16 = lane & 15;
    int row0 = blockIdx.x * 128 + wv * 32;
    f32x4 acc[2][CT] = {};
#pragma unroll
    for (int ks = 0; ks < 4; ks++) {
        int k0 = ks * 32 + quad * 8;
        bf16x8 a[2];
#pragma unroll
        for (int rt = 0; rt < 2; rt++) {
            int r = row0 + rt * 16 + l16;
            if (r >= N) r = N - 1;
            const TIN* p = X + (size_t)r * 128 + k0;
            if constexpr (sizeof(TIN) == 4) {
                f32x4 x0 = *(const f32x4*)p;
                f32x4 x1 = *(const f32x4*)(p + 4);
                bf16x8 tt;
                tt[0] = (bf16_t)x0[0]; tt[1] = (bf16_t)x0[1];
                tt[2] = (bf16_t)x0[2]; tt[3] = (bf16_t)x0[3];
                tt[4] = (bf16_t)x1[0]; tt[5] = (bf16_t)x1[1];
                tt[6] = (bf16_t)x1[2]; tt[7] = (bf16_t)x1[3];
                a[rt] = tt;
            } else {
                a[rt] = *(const bf16x8*)p;
            }
        }
#pragma unroll
        for (int ct = 0; ct < CT; ct++) {
            bf16x8 bfrag = *(const bf16x8*)(W + (size_t)(ct * 16 + l16) * 128 + k0);
#pragma unroll
            for (int rt = 0; rt < 2; rt++)
                acc[rt][ct] = __builtin_amdgcn_mfma_f32_16x16x32_bf16(a[rt], bfrag, acc[rt][ct], 0, 0, 0);
        }
    }
#pragma unroll
    for (int rt = 0; rt < 2; rt++)
#pragma unroll
        for (int r4 = 0; r4 < 4; r4++) {
            int r = row0 + rt * 16 + quad * 4 + r4;
            if (r < N) {
                float sc = scale[r];
#pragma unroll
                for (int ct = 0; ct < CT; ct++)
                    H[(size_t)r * NCOL + ct * 16 + l16] = (bf16_t)(sc * acc[rt][ct][r4]);
            } else if (r == N) {
#pragma unroll
                for (int ct = 0; ct < CT; ct++)
                    H[(size_t)N * NCOL + ct * 16 + l16] = (bf16_t)0.f;
            }
        }
}

// ---------------- gather helpers ----------------
template <int ROWE>
__device__ __forceinline__ void gather8(const bf16_t* __restrict__ hp,
                                        const int* __restrict__ col, int e,
                                        u32x4* w) {
    int4 c0 = *(const int4*)(col + e);
    int4 c1 = *(const int4*)(col + e + 4);
    w[0] = *(const u32x4*)(hp + (unsigned)c0.x * (unsigned)ROWE);
    w[1] = *(const u32x4*)(hp + (unsigned)c0.y * (unsigned)ROWE);
    w[2] = *(const u32x4*)(hp + (unsigned)c0.z * (unsigned)ROWE);
    w[3] = *(const u32x4*)(hp + (unsigned)c0.w * (unsigned)ROWE);
    w[4] = *(const u32x4*)(hp + (unsigned)c1.x * (unsigned)ROWE);
    w[5] = *(const u32x4*)(hp + (unsigned)c1.y * (unsigned)ROWE);
    w[6] = *(const u32x4*)(hp + (unsigned)c1.z * (unsigned)ROWE);
    w[7] = *(const u32x4*)(hp + (unsigned)c1.w * (unsigned)ROWE);
}

__device__ __forceinline__ void accum8(const u32x4* w, f32x2* a2) {
#pragma unroll
    for (int u = 0; u < 8; u++)
#pragma unroll
        for (int k = 0; k < 4; k++) {
            f32x2 v;
            v.x = __uint_as_float(w[u][k] << 16);
            v.y = __uint_as_float(w[u][k] & 0xffff0000u);
            a2[k] += v;                       // v_pk_add_f32
        }
}

// ---------------- fused agg128 + gemm64 (layer-1 agg + layer-2 GEMM) -------
// 16 lanes/node, 4 nodes/wave, 16 nodes/block. Aggregate h1 + relu in regs,
// stage the 16x128 tile in LDS, then 4-wave MFMA 128->64 with dinv scale,
// writing h2 bf16 (+ zero row N). h1r never touches global memory.
__global__ __launch_bounds__(256) void k_agg_gemm(const bf16_t* __restrict__ h,
                                                  const int2* __restrict__ off2,
                                                  const int* __restrict__ col,
                                                  const float* __restrict__ dinv,
                                                  const float* __restrict__ bias,
                                                  const bf16_t* __restrict__ W2,
                                                  bf16_t* __restrict__ h2, int N) {
    __shared__ float hl[16][132];   // +4 pad: 2-way-max bank aliasing
    __shared__ float dl[16];
    int lane = threadIdx.x & 63;
    int wv = threadIdx.x >> 6;
    int g = lane >> 4, fl = lane & 15;
    int node0 = blockIdx.x * 16;
    int node = node0 + wv * 4 + g;
    bool alive = node < N;
    int f = fl * 8;
    const bf16_t* hp = h + f;
    f32x2 a2[4] = {};
    float di = 0.f;
    if (alive) {
        u32x4 ws = *(const u32x4*)(hp + (unsigned)node * 128u);   // self row
        int2 oe = off2[node];
        di = dinv[node];
#pragma unroll
        for (int k = 0; k < 4; k++) {
            f32x2 v;
            v.x = __uint_as_float(ws[k] << 16);
            v.y = __uint_as_float(ws[k] & 0xffff0000u);
            a2[k] = v;
        }
        u32x4 w[8];
        for (int e = oe.x; e < oe.y; e += 8) {
            gather8<128>(hp, col, e, w);
            accum8(w, a2);
        }
    }
    f32x4 b0 = *(const f32x4*)(bias + f);
    f32x4 b1 = *(const f32x4*)(bias + f + 4);
    int lr = wv * 4 + g;
#pragma unroll
    for (int j = 0; j < 8; j++) {
        float bv = (j < 4) ? b0[j] : b1[j - 4];
        float val = a2[j >> 1][j & 1] * di + bv;
        hl[lr][f + j] = fmaxf(val, 0.f);        // relu'd h1r row in LDS
    }
    if (fl == 0) dl[lr] = di;
    __syncthreads();

    // mini-GEMM: wave wv computes output cols [wv*16, wv*16+16)
    int quad = lane >> 4, l16 = lane & 15;
    f32x4 c4 = {0.f, 0.f, 0.f, 0.f};
#pragma unroll
    for (int ks = 0; ks < 4; ks++) {
        int k0 = ks * 32 + quad * 8;
        bf16x8 afr;
#pragma unroll
        for (int j = 0; j < 8; j++) afr[j] = (bf16_t)hl[l16][k0 + j];
        bf16x8 bfr = *(const bf16x8*)(W2 + (size_t)(wv * 16 + l16) * 128 + k0);
        c4 = __builtin_amdgcn_mfma_f32_16x16x32_bf16(afr, bfr, c4, 0, 0, 0);
    }
#pragma unroll
    for (int r4 = 0; r4 < 4; r4++) {
        int rr = quad * 4 + r4;
        int gn = node0 + rr;
        if (gn < N)
            h2[(size_t)gn * 64 + wv * 16 + l16] = (bf16_t)(dl[rr] * c4[r4]);
    }
    if (blockIdx.x == 0 && threadIdx.x < 32)    // zero sentinel row N of h2
        ((unsigned*)h2)[(size_t)N * 32 + threadIdx.x] = 0u;
}

// ---------------- agg, generic: LPN lanes/node, 64/LPN nodes/wave ---------
template <int ROWE, int LPN, bool RELU, typename TOUT>
__global__ __launch_bounds__(256) void k_agg(const bf16_t* __restrict__ h,
                                             const int2* __restrict__ off2,
                                             const int* __restrict__ col,
                                             const float* __restrict__ dinv,
                                             const float* __restrict__ bias,
                                             TOUT* __restrict__ out, int N) {
    constexpr int NPW = 64 / LPN;   // nodes per wave
    int lane = threadIdx.x & 63;
    int wv = threadIdx.x >> 6;
    int g = lane / LPN, fl = lane % LPN;
    int node = blockIdx.x * (4 * NPW) + wv * NPW + g;
    if (node >= N) return;
    int f = fl * 8;
    const bf16_t* hp = h + f;
    u32x4 ws = *(const u32x4*)(hp + (unsigned)node * (unsigned)ROWE); // self row
    int2 oe = off2[node];
    float di = dinv[node];
    f32x2 a2[4];
#pragma unroll
    for (int k = 0; k < 4; k++) {
        f32x2 v;
        v.x = __uint_as_float(ws[k] << 16);
        v.y = __uint_as_float(ws[k] & 0xffff0000u);
        a2[k] = v;
    }
    u32x4 w[8];
    for (int e = oe.x; e < oe.y; e += 8) {
        gather8<ROWE>(hp, col, e, w);
        accum8(w, a2);
    }
    f32x4 b0 = *(const f32x4*)(bias + f);
    f32x4 b1 = *(const f32x4*)(bias + f + 4);
    float r[8];
#pragma unroll
    for (int j = 0; j < 8; j++) {
        float bv = (j < 4) ? b0[j] : b1[j - 4];
        float val = a2[j >> 1][j & 1] * di + bv;
        if (RELU) val = fmaxf(val, 0.f);
        r[j] = val;
    }
    if constexpr (sizeof(TOUT) == 2) {
        bf16x8 v;
#pragma unroll
        for (int j = 0; j < 8; j++) v[j] = (bf16_t)r[j];
        *(bf16x8*)((bf16_t*)out + (size_t)node * ROWE + f) = v;
    } else {
        f32x4 v0 = {r[0], r[1], r[2], r[3]};
        f32x4 v1 = {r[4], r[5], r[6], r[7]};
        *(f32x4*)((float*)out + (size_t)node * ROWE + f) = v0;
        *(f32x4*)((float*)out + (size_t)node * ROWE + f + 4) = v1;
    }
}

extern "C" void kernel_launch(void* const* d_in, const int* in_sizes, int n_in,
                              void* d_out, int out_size, void* d_ws, size_t ws_size,
                              hipStream_t stream) {
    const float* x  = (const float*)d_in[0];
    const float* W1 = (const float*)d_in[1];
    const float* b1 = (const float*)d_in[2];
    const float* W2 = (const float*)d_in[3];
    const float* b2 = (const float*)d_in[4];
    const int*   ei = (const int*)d_in[5];

    int N = in_sizes[0] / IN_F;
    int E = in_sizes[5] / 2;
    const int* src = ei;
    const int* dst = ei + E;
    int NBKT = (N + NPB - 1) / NPB;           // 196
    int pchunks = (E + CHUNK - 1) / CHUNK;    // 391

    size_t woff = 0;
    auto alloc = [&](size_t bytes) {
        void* p = (char*)d_ws + woff;
        woff += (bytes + 255) & ~(size_t)255;
        return p;
    };
    int*      bcur  = (int*)alloc((size_t)NBKT * 16 * 4);   // 64B line per bucket
    unsigned* part  = (unsigned*)alloc((size_t)NBKT * SLAB * 4);
    int*      col   = (int*)alloc((size_t)NBKT * SLAB * 4);
    int2*     off2  = (int2*)alloc((size_t)N * 8);
    float*    dinv  = (float*)alloc((size_t)N * 4);
    bf16_t*   Wb    = (bf16_t*)alloc((size_t)(HID_F * IN_F + OUT_F * HID_F) * 2);
    bf16_t*   W1b   = Wb;
    bf16_t*   W2b   = Wb + HID_F * IN_F;
    bf16_t*   h1    = (bf16_t*)alloc((size_t)(N + 1) * HID_F * 2);  // +1 zero row
    bf16_t*   h2b   = (bf16_t*)alloc((size_t)(N + 1) * OUT_F * 2);  // +1 zero row
    float*    outp  = (float*)d_out;

    int n1 = HID_F * IN_F, n2 = OUT_F * HID_F;
    int preblocks = (n1 + n2) / 256 + 1;      // 96 conv blocks + 1 bcur block
    k_pre<<<preblocks, 256, 0, stream>>>(W1, W2, Wb, n1, n2, bcur, NBKT * 16);
    k_part<<<pchunks, 256, 0, stream>>>(src, dst, E, bcur, part, NBKT);
    k_bucket<<<NBKT, 512, 0, stream>>>(part, bcur, off2, col, dinv, N);

    int gemm_blocks = (N + 127) / 128;

    // layer 1: h1 = dinv * (x@W1^T)  [bf16, +zero row N]
    k_gemm_mfma<HID_F, float><<<gemm_blocks, 256, 0, stream>>>(x, W1b, dinv, h1, N);
    // fused: agg(h1)+relu -> (in LDS) @ W2^T -> dinv-scale -> h2 [bf16]
    k_agg_gemm<<<(N + 15) / 16, 256, 0, stream>>>(h1, off2, col, dinv, b1, W2b, h2b, N);
    // layer 2 agg: gather h2 -> fp32 out
    k_agg<OUT_F, 8, false, float><<<(N + 31) / 32, 256, 0, stream>>>(h2b, off2, col, dinv, b2, outp, N);
}